// Round 1
// baseline (535.138 us; speedup 1.0000x reference)
//
#include <hip/hip_runtime.h>
#include <math.h>

// Problem dims (fixed by reference setup_inputs):
//   video [B=8, C=1024, T=64, W=14, H=14] fp32 ; mu/sigma [N=3] fp32
//   out   [B, C*N] fp32, out[b, c*3+n] = (1/T) * sum_{t,w,h} video[b,c,t,w,h]*f[n,w,h]
#define B_  8
#define C_  1024
#define T_  64
#define W_  14
#define H_  14
#define N_  3
#define WH  (W_ * H_)    // 196 floats per (t) frame
#define WH4 (WH / 4)     // 49 float4 per frame (exact: 196 % 4 == 0)

// One wave (64 lanes) per (b,c). Lane l < 49 owns float4-column l of the
// [T,WH] slab; its 12 filter weights live in registers (loop-invariant).
__global__ void attn_pool_kernel(const float* __restrict__ video,
                                 const float* __restrict__ mu_x,
                                 const float* __restrict__ mu_y,
                                 const float* __restrict__ sigma_x,
                                 const float* __restrict__ sigma_y,
                                 float* __restrict__ out)
{
    const int wave = threadIdx.x >> 6;
    const int lane = threadIdx.x & 63;
    const int bc   = blockIdx.x * 4 + wave;   // [0, B_*C_)

    // ---- per-lane filter fragment f[n][j], wh = 4*lane + j ----
    float fv[N_][4];
#pragma unroll
    for (int n = 0; n < N_; ++n)
#pragma unroll
        for (int j = 0; j < 4; ++j) fv[n][j] = 0.0f;

    if (lane < WH4) {
#pragma unroll
        for (int n = 0; n < N_; ++n) {
            // squash params exactly as reference
            const float mux  = 6.5f * (tanhf(mu_x[n]) + 1.0f);   // (W-1)*(tanh+1)/2
            const float muy  = 6.5f * (tanhf(mu_y[n]) + 1.0f);
            const float sgx  = 1.0f / (1.0f + expf(-sigma_x[n]));
            const float sgy  = 1.0f / (1.0f + expf(-sigma_y[n]));
            // sx^2 = exp(2*(1.5 - 2*sig)) = exp(3 - 4*sig)
            const float invx = 1.0f / (expf(3.0f - 4.0f * sgx) + 1e-6f);
            const float invy = 1.0f / (expf(3.0f - 4.0f * sgy) + 1e-6f);
#pragma unroll
            for (int j = 0; j < 4; ++j) {
                const int   wh = 4 * lane + j;
                const int   w  = wh / H_;
                const int   h  = wh - w * H_;
                const float dx = (float)w - mux;
                const float dy = (float)h - muy;
                fv[n][j] = expf(-0.5f * (dx * dx * invx + dy * dy * invy));
            }
        }
    }
    // normalize: f /= (sum_{w,h} f + 1e-6), sum via wave butterfly
#pragma unroll
    for (int n = 0; n < N_; ++n) {
        float s = fv[n][0] + fv[n][1] + fv[n][2] + fv[n][3];
#pragma unroll
        for (int off = 32; off > 0; off >>= 1) s += __shfl_xor(s, off);
        const float norm = 1.0f / (s + 1e-6f);
#pragma unroll
        for (int j = 0; j < 4; ++j) fv[n][j] *= norm;
    }

    // ---- stream the [T, WH] slab: 1 float4 load + 12 FMA per t ----
    const float4* v4 = (const float4*)(video + (size_t)bc * (size_t)(T_ * WH));
    float a0 = 0.0f, a1 = 0.0f, a2 = 0.0f;
    if (lane < WH4) {
#pragma unroll 8
        for (int t = 0; t < T_; ++t) {
            const float4 v = v4[t * WH4 + lane];
            a0 += v.x * fv[0][0] + v.y * fv[0][1] + v.z * fv[0][2] + v.w * fv[0][3];
            a1 += v.x * fv[1][0] + v.y * fv[1][1] + v.z * fv[1][2] + v.w * fv[1][3];
            a2 += v.x * fv[2][0] + v.y * fv[2][1] + v.z * fv[2][2] + v.w * fv[2][3];
        }
    }
    // wave-reduce the 3 accumulators (idle lanes contribute 0)
#pragma unroll
    for (int off = 32; off > 0; off >>= 1) {
        a0 += __shfl_xor(a0, off);
        a1 += __shfl_xor(a1, off);
        a2 += __shfl_xor(a2, off);
    }
    if (lane == 0) {
        float* o = out + (size_t)bc * N_;   // b*C*N + c*N == bc*N
        o[0] = a0 * (1.0f / T_);
        o[1] = a1 * (1.0f / T_);
        o[2] = a2 * (1.0f / T_);
    }
}

extern "C" void kernel_launch(void* const* d_in, const int* in_sizes, int n_in,
                              void* d_out, int out_size, void* d_ws, size_t ws_size,
                              hipStream_t stream) {
    const float* video   = (const float*)d_in[0];
    const float* mu_x    = (const float*)d_in[1];
    const float* mu_y    = (const float*)d_in[2];
    const float* sigma_x = (const float*)d_in[3];
    const float* sigma_y = (const float*)d_in[4];
    float* out = (float*)d_out;

    const int waves  = B_ * C_;        // 8192 (b,c) pairs, one wave each
    const int blocks = waves / 4;      // 4 waves per 256-thread block
    attn_pool_kernel<<<blocks, 256, 0, stream>>>(video, mu_x, mu_y,
                                                 sigma_x, sigma_y, out);
}